// Round 11
// baseline (312.301 us; speedup 1.0000x reference)
//
#include <hip/hip_runtime.h>
#include <hip/hip_bf16.h>

// Problem constants
#define BB   8
#define NN   4096
#define DD   512
#define HH   8
#define DHH  64
#define WW   128
#define PP   32      // windows = NN / WW
#define DISP 64

typedef __attribute__((ext_vector_type(8))) short bf16x8_t;       // 8 bf16 (4 VGPRs)
typedef __attribute__((ext_vector_type(4))) float f32x4_t;        // MFMA C/D
typedef __attribute__((ext_vector_type(8))) unsigned short u16x8; // raw bf16 bits

__device__ __forceinline__ unsigned short f2bf(float f) {
    unsigned int u = __float_as_uint(f);
    unsigned int r = (u + 0x7FFFu + ((u >> 16) & 1u)) >> 16;  // RNE
    return (unsigned short)r;
}
__device__ __forceinline__ float bf2f(unsigned short u) {
    return __uint_as_float(((unsigned int)u) << 16);
}

__device__ __forceinline__ void gload_lds16(const void* g, void* l) {
    __builtin_amdgcn_global_load_lds(
        (const __attribute__((address_space(1))) unsigned int*)g,
        (__attribute__((address_space(3))) unsigned int*)l, 16, 0, 0);
}

// ---------------------------------------------------------------------------
// Convert x (fp32) -> xb (bf16), applying cyclic shift roll(x,-DISP) so that
// xb rows are in SHIFTED token order (GEMM A reads become linear).
// ---------------------------------------------------------------------------
__global__ __launch_bounds__(256) void cvt_x_shift(const float* __restrict__ x,
                                                   unsigned short* __restrict__ xb) {
    int idx = blockIdx.x * 256 + threadIdx.x;     // 8192*256 threads, 8 elems each
    int e0 = idx * 8;
    int r = e0 >> 9, d = e0 & 511;
    int b = r >> 12, n = r & 4095;
    const float* src = x + (size_t)((b << 12) | ((n + DISP) & 4095)) * 512 + d;
    float4 f0 = *(const float4*)src;
    float4 f1 = *(const float4*)(src + 4);
    u16x8 p;
    p[0] = f2bf(f0.x); p[1] = f2bf(f0.y); p[2] = f2bf(f0.z); p[3] = f2bf(f0.w);
    p[4] = f2bf(f1.x); p[5] = f2bf(f1.y); p[6] = f2bf(f1.z); p[7] = f2bf(f1.w);
    *(u16x8*)(xb + (size_t)r * 512 + d) = p;
}

// ---------------------------------------------------------------------------
// Convert + transpose weights: WqkvT[n][k] (1536x512), WoutT[n][k] (512x512)
// ---------------------------------------------------------------------------
__global__ __launch_bounds__(256) void cvt_w(const float* __restrict__ Wqkv,
                                             const float* __restrict__ Wout,
                                             unsigned short* __restrict__ wqkvT,
                                             unsigned short* __restrict__ woutT) {
    int idx = blockIdx.x * 256 + threadIdx.x;    // 4096*256 = 1,048,576
    if (idx < 786432) {
        int n = idx >> 9, k = idx & 511;
        wqkvT[idx] = f2bf(Wqkv[(size_t)k * 1536 + n]);
    } else {
        int j = idx - 786432;
        int n = j >> 9, k = j & 511;
        woutT[j] = f2bf(Wout[(size_t)k * 512 + n]);
    }
}

// ---------------------------------------------------------------------------
// bf16 MFMA GEMM for QKV, WINDOW-ALIGNED tiling (proven r10: WRITE 430->100MB)
// + BK=64 this round: halves barrier drains (16->8), doubles MFMA/phase,
// A-row segments 64B->128B (full cache lines on the stride-32 token rows).
//   window base = ((b*8+h)*32+pi)*8192   (16KB block per (b,h,window))
//   q: plain      [w][dh]            -> base + w*64 + dh
//   k: swizzled   [w][dh]            -> base + w*64 + (dh ^ ((w&7)<<3))
//   v: transposed [dh][w], swizzled  -> base + dh*128 + (w ^ ((dh&7)<<3))
// ---------------------------------------------------------------------------
__global__ __launch_bounds__(256) void gemm_qkv(const unsigned short* __restrict__ A,
                                                const unsigned short* __restrict__ BT,
                                                unsigned short* __restrict__ qw,
                                                unsigned short* __restrict__ kw,
                                                unsigned short* __restrict__ vw) {
    __shared__ unsigned short As[128 * 64];   // 16KB, [row][k] row-major
    __shared__ unsigned short Bs[128 * 64];   // 16KB
    const int tid  = threadIdx.x;
    const int wv   = tid >> 6, lane = tid & 63;
    const int brow = blockIdx.x;            // 256 = b*32 + pi
    const int bcol = blockIdx.y;            // 12
    const int b  = brow >> 5, pi = brow & 31;
    const int wr = (wv >> 1) * 64, wc = (wv & 1) * 64;
    const int lr = lane >> 4, lc = lane & 15;
    const int kq = lr * 8;
    const int srow = lane >> 3;             // staging: lane's row within 8-row group
    const int ske  = (lane & 7) * 8;        // staging: lane's k-offset (elems)

    f32x4_t acc[4][4];
#pragma unroll
    for (int i = 0; i < 4; ++i)
#pragma unroll
        for (int j = 0; j < 4; ++j) acc[i][j] = (f32x4_t)0.f;

    // A row for tile-row m (= window token w): b*4096 + m*32 + pi
    const size_t abase = ((size_t)b * 4096 + pi) * 512;
    const size_t brow0 = (size_t)bcol * 128;

    for (int k0 = 0; k0 < 512; k0 += 64) {
        // stage 128x64 A and B tiles: 16 groups of 8 rows; wave wv owns 4 each
#pragma unroll
        for (int i = 0; i < 4; ++i) {
            int g = wv * 4 + i;                 // 8-row group
            int row = g * 8 + srow;             // 0..127 (= token w)
            gload_lds16(A  + abase + (size_t)row * 16384 + k0 + ske, &As[g * 512]);
            gload_lds16(BT + (brow0 + row) * 512 + k0 + ske, &Bs[g * 512]);
        }
        __syncthreads();
#pragma unroll
        for (int ks = 0; ks < 2; ++ks) {
            bf16x8_t af[4], bfr[4];
#pragma unroll
            for (int mi = 0; mi < 4; ++mi)
                af[mi] = *(const bf16x8_t*)&As[(wr + mi * 16 + lc) * 64 + ks * 32 + kq];
#pragma unroll
            for (int nj = 0; nj < 4; ++nj)
                bfr[nj] = *(const bf16x8_t*)&Bs[(wc + nj * 16 + lc) * 64 + ks * 32 + kq];
#pragma unroll
            for (int mi = 0; mi < 4; ++mi)
#pragma unroll
                for (int nj = 0; nj < 4; ++nj)
                    acc[mi][nj] = __builtin_amdgcn_mfma_f32_16x16x32_bf16(
                        af[mi], bfr[nj], acc[mi][nj], 0, 0, 0);
        }
        __syncthreads();
    }

    // Epilogue: C row = (lane>>4)*4+reg (= token w), col = lane&15 in frag
#pragma unroll
    for (int nj = 0; nj < 4; ++nj) {
        int c = bcol * 128 + wc + nj * 16 + lc;
        int which = c >> 9;
        int h  = (c >> 6) & 7;
        int dh = c & 63;
        unsigned short* dst = (which == 0) ? qw : ((which == 1) ? kw : vw);
        size_t base = ((size_t)((b * 8 + h) * 32 + pi)) * 8192;
#pragma unroll
        for (int mi = 0; mi < 4; ++mi)
#pragma unroll
            for (int r = 0; r < 4; ++r) {
                int w = wr + mi * 16 + lr * 4 + r;   // tile row = window token
                size_t off;
                if (which == 0)      off = base + (size_t)w * 64 + dh;
                else if (which == 1) off = base + (size_t)w * 64 + (dh ^ ((w & 7) << 3));
                else                 off = base + (size_t)dh * 128 + (w ^ ((dh & 7) << 3));
                dst[off] = f2bf(acc[mi][nj][r]);
            }
    }
}

// ---------------------------------------------------------------------------
// out_proj GEMM: out = roll(ao @ Wout + bout, +DISP).  BK=64 (same template).
// ---------------------------------------------------------------------------
__global__ __launch_bounds__(256) void gemm_out(const unsigned short* __restrict__ A,
                                                const unsigned short* __restrict__ BT,
                                                const float* __restrict__ bout,
                                                float* __restrict__ out) {
    __shared__ unsigned short As[128 * 64];
    __shared__ unsigned short Bs[128 * 64];
    const int tid  = threadIdx.x;
    const int wv   = tid >> 6, lane = tid & 63;
    const int brow = blockIdx.x;            // 256
    const int bcol = blockIdx.y;            // 4
    const int wr = (wv >> 1) * 64, wc = (wv & 1) * 64;
    const int lr = lane >> 4, lc = lane & 15;
    const int kq = lr * 8;
    const int srow = lane >> 3;
    const int ske  = (lane & 7) * 8;

    f32x4_t acc[4][4];
#pragma unroll
    for (int i = 0; i < 4; ++i)
#pragma unroll
        for (int j = 0; j < 4; ++j) acc[i][j] = (f32x4_t)0.f;

    const size_t arow0 = (size_t)brow * 128;
    const size_t brow0 = (size_t)bcol * 128;

    for (int k0 = 0; k0 < 512; k0 += 64) {
#pragma unroll
        for (int i = 0; i < 4; ++i) {
            int g = wv * 4 + i;
            int row = g * 8 + srow;
            gload_lds16(A  + (arow0 + row) * 512 + k0 + ske, &As[g * 512]);
            gload_lds16(BT + (brow0 + row) * 512 + k0 + ske, &Bs[g * 512]);
        }
        __syncthreads();
#pragma unroll
        for (int ks = 0; ks < 2; ++ks) {
            bf16x8_t af[4], bfr[4];
#pragma unroll
            for (int mi = 0; mi < 4; ++mi)
                af[mi] = *(const bf16x8_t*)&As[(wr + mi * 16 + lc) * 64 + ks * 32 + kq];
#pragma unroll
            for (int nj = 0; nj < 4; ++nj)
                bfr[nj] = *(const bf16x8_t*)&Bs[(wc + nj * 16 + lc) * 64 + ks * 32 + kq];
#pragma unroll
            for (int mi = 0; mi < 4; ++mi)
#pragma unroll
                for (int nj = 0; nj < 4; ++nj)
                    acc[mi][nj] = __builtin_amdgcn_mfma_f32_16x16x32_bf16(
                        af[mi], bfr[nj], acc[mi][nj], 0, 0, 0);
        }
        __syncthreads();
    }

#pragma unroll
    for (int nj = 0; nj < 4; ++nj) {
        int c = bcol * 128 + wc + nj * 16 + lc;
        float bias = bout[c];
#pragma unroll
        for (int mi = 0; mi < 4; ++mi)
#pragma unroll
            for (int r = 0; r < 4; ++r) {
                int row = brow * 128 + wr + mi * 16 + lr * 4 + r;
                int b = row >> 12, np = row & 4095;
                int dn = (np + DISP) & 4095;                 // roll(+DISP)
                out[(size_t)((b << 12) | dn) * 512 + c] = acc[mi][nj][r] + bias;
            }
    }
}

// ---------------------------------------------------------------------------
// win_attn (MFMA): one block per (b,h,pi) window; 4 waves, wave wv owns
// q-rows [wv*32, wv*32+32).  S kept in accumulators; wave-parallel softmax;
// P through per-wave swizzled LDS; PV via MFMA with transposed V.
// ---------------------------------------------------------------------------
__global__ __launch_bounds__(256) void win_attn(const unsigned short* __restrict__ qw,
                                                const unsigned short* __restrict__ kw,
                                                const unsigned short* __restrict__ vw,
                                                const float* __restrict__ pos,
                                                unsigned short* __restrict__ aob) {
    __shared__ unsigned short K_lds[8192];        // 16KB, [w][dh] swizzled
    __shared__ unsigned short V_lds[8192];        // 16KB, [dh][w] swizzled
    __shared__ unsigned short P_lds[4][4096];     // 8KB per wave, [r][j] swizzled
    __shared__ float pos_lds[255];

    const int tid  = threadIdx.x;
    const int wv   = tid >> 6, lane = tid & 63;
    const int lr   = lane >> 4, lc = lane & 15;
    const int blk  = blockIdx.x;        // b*256 + h*32 + pi
    const int pi   = blk & 31;
    const int h    = (blk >> 5) & 7;
    const int b    = blk >> 8;
    const size_t base = ((size_t)((b * 8 + h) * 32 + pi)) * 8192;
    const unsigned short* qg = qw + base;
    const unsigned short* kg = kw + base;
    const unsigned short* vg = vw + base;

    if (tid < 255) pos_lds[tid] = pos[tid];

    // stage K, V linearly (global layout == LDS image)
#pragma unroll
    for (int i = 0; i < 4; ++i) {
        int c = wv * 4 + i;
        gload_lds16(kg + c * 512 + lane * 8, &K_lds[c * 512]);
        gload_lds16(vg + c * 512 + lane * 8, &V_lds[c * 512]);
    }

    // Q fragments direct from global (plain [w][dh] layout)
    bf16x8_t qf[2][2];
#pragma unroll
    for (int mi = 0; mi < 2; ++mi)
#pragma unroll
        for (int ks = 0; ks < 2; ++ks)
            qf[mi][ks] = *(const bf16x8_t*)(qg + (wv * 32 + mi * 16 + lc) * 64 + ks * 32 + lr * 8);

    __syncthreads();

    // ---- QK^T: S[32][128] per wave in accumulators -------------------------
    f32x4_t sa[2][8];
#pragma unroll
    for (int mi = 0; mi < 2; ++mi)
#pragma unroll
        for (int nj = 0; nj < 8; ++nj) sa[mi][nj] = (f32x4_t)0.f;

#pragma unroll
    for (int ks = 0; ks < 2; ++ks) {
#pragma unroll
        for (int nj = 0; nj < 8; ++nj) {
            int row = nj * 16 + lc;
            int byteoff = ((row * 128) + (ks * 32 + lr * 8) * 2) ^ ((row & 7) << 4);
            bf16x8_t kf = *(const bf16x8_t*)((const char*)K_lds + byteoff);
            sa[0][nj] = __builtin_amdgcn_mfma_f32_16x16x32_bf16(qf[0][ks], kf, sa[0][nj], 0, 0, 0);
            sa[1][nj] = __builtin_amdgcn_mfma_f32_16x16x32_bf16(qf[1][ks], kf, sa[1][nj], 0, 0, 0);
        }
    }

    // ---- bias + mask + wave-parallel softmax; P -> per-wave LDS (bf16) -----
    // lane holds S[i][j]: i = wv*32 + mi*16 + lr*4 + r, j = nj*16 + lc
#pragma unroll
    for (int mi = 0; mi < 2; ++mi)
#pragma unroll
        for (int r = 0; r < 4; ++r) {
            int i = wv * 32 + mi * 16 + lr * 4 + r;
            float mx = -3.0e38f;
#pragma unroll
            for (int nj = 0; nj < 8; ++nj) {
                int j = nj * 16 + lc;
                float s = fmaf(sa[mi][nj][r], 0.125f, pos_lds[j - i + 127]);
                if ((i >= 64) != (j >= 64)) s -= 1e9f;   // shift mask
                sa[mi][nj][r] = s;
                mx = fmaxf(mx, s);
            }
            mx = fmaxf(mx, __shfl_xor(mx, 1));
            mx = fmaxf(mx, __shfl_xor(mx, 2));
            mx = fmaxf(mx, __shfl_xor(mx, 4));
            mx = fmaxf(mx, __shfl_xor(mx, 8));
            float sum = 0.f;
#pragma unroll
            for (int nj = 0; nj < 8; ++nj) {
                float e = __expf(sa[mi][nj][r] - mx);
                sa[mi][nj][r] = e;
                sum += e;
            }
            sum += __shfl_xor(sum, 1);
            sum += __shfl_xor(sum, 2);
            sum += __shfl_xor(sum, 4);
            sum += __shfl_xor(sum, 8);
            float inv = 1.0f / sum;
            int rloc = mi * 16 + lr * 4 + r;
#pragma unroll
            for (int nj = 0; nj < 8; ++nj) {
                int j = nj * 16 + lc;
                int byteoff = ((rloc * 256) + j * 2) ^ ((rloc & 7) << 4);
                *(unsigned short*)((char*)P_lds[wv] + byteoff) = f2bf(sa[mi][nj][r] * inv);
            }
        }
    // (no barrier: P_lds[wv] is same-wave RAW; compiler inserts lgkmcnt)

    // ---- PV: O[32][64] per wave ------------------------------------------
    f32x4_t oa[2][4];
#pragma unroll
    for (int mi = 0; mi < 2; ++mi)
#pragma unroll
        for (int nj = 0; nj < 4; ++nj) oa[mi][nj] = (f32x4_t)0.f;

#pragma unroll
    for (int ks = 0; ks < 4; ++ks) {
        bf16x8_t pa[2], vb[4];
#pragma unroll
        for (int mi = 0; mi < 2; ++mi) {
            int rloc = mi * 16 + lc;
            int byteoff = ((rloc * 256) + (ks * 32 + lr * 8) * 2) ^ ((rloc & 7) << 4);
            pa[mi] = *(const bf16x8_t*)((const char*)P_lds[wv] + byteoff);
        }
#pragma unroll
        for (int nj = 0; nj < 4; ++nj) {
            int dh = nj * 16 + lc;
            int byteoff = ((dh * 256) + (ks * 32 + lr * 8) * 2) ^ ((dh & 7) << 4);
            vb[nj] = *(const bf16x8_t*)((const char*)V_lds + byteoff);
        }
#pragma unroll
        for (int mi = 0; mi < 2; ++mi)
#pragma unroll
            for (int nj = 0; nj < 4; ++nj)
                oa[mi][nj] = __builtin_amdgcn_mfma_f32_16x16x32_bf16(pa[mi], vb[nj], oa[mi][nj], 0, 0, 0);
    }

    // ---- epilogue: O row w -> ao token n' = pi*128 + w ---------------------
    const size_t orow0 = (size_t)b * 4096 + (size_t)pi * 128;
#pragma unroll
    for (int mi = 0; mi < 2; ++mi)
#pragma unroll
        for (int r = 0; r < 4; ++r) {
            int w = wv * 32 + mi * 16 + lr * 4 + r;
            unsigned short* dst = aob + (orow0 + w) * 512 + h * 64;
#pragma unroll
            for (int nj = 0; nj < 4; ++nj)
                dst[nj * 16 + lc] = f2bf(oa[mi][nj][r]);
        }
}

// ---------------------------------------------------------------------------
extern "C" void kernel_launch(void* const* d_in, const int* in_sizes, int n_in,
                              void* d_out, int out_size, void* d_ws, size_t ws_size,
                              hipStream_t stream) {
    (void)in_sizes; (void)n_in; (void)out_size; (void)ws_size;
    const float* x    = (const float*)d_in[0];
    const float* Wqkv = (const float*)d_in[1];
    const float* pos  = (const float*)d_in[2];
    const float* Wout = (const float*)d_in[3];
    const float* bout = (const float*)d_in[4];
    float* out = (float*)d_out;

    const size_t T = (size_t)BB * NN * 512;   // 16,777,216 elems
    unsigned short* xb    = (unsigned short*)d_ws;
    unsigned short* wqkvT = xb + T;           // 786,432
    unsigned short* woutT = wqkvT + 786432;   // 262,144
    unsigned short* qw    = woutT + 262144;
    unsigned short* kw    = qw + T;
    unsigned short* vw    = kw + T;
    unsigned short* aob   = vw + T;

    cvt_x_shift<<<dim3(8192), 256, 0, stream>>>(x, xb);
    cvt_w<<<dim3(4096), 256, 0, stream>>>(Wqkv, Wout, wqkvT, woutT);
    gemm_qkv<<<dim3(256, 12), 256, 0, stream>>>(xb, wqkvT, qw, kw, vw);
    win_attn<<<dim3(2048), 256, 0, stream>>>(qw, kw, vw, pos, aob);
    gemm_out<<<dim3(256, 4), 256, 0, stream>>>(aob, woutT, bout, out);
}

// Round 12
// 311.483 us; speedup vs baseline: 1.0026x; 1.0026x over previous
//
#include <hip/hip_runtime.h>
#include <hip/hip_bf16.h>

// Problem constants
#define BB   8
#define NN   4096
#define DD   512
#define HH   8
#define DHH  64
#define WW   128
#define PP   32      // windows = NN / WW
#define DISP 64

typedef __attribute__((ext_vector_type(8))) short bf16x8_t;       // 8 bf16 (4 VGPRs)
typedef __attribute__((ext_vector_type(4))) float f32x4_t;        // MFMA C/D
typedef __attribute__((ext_vector_type(8))) unsigned short u16x8; // raw bf16 bits

__device__ __forceinline__ unsigned short f2bf(float f) {
    unsigned int u = __float_as_uint(f);
    unsigned int r = (u + 0x7FFFu + ((u >> 16) & 1u)) >> 16;  // RNE
    return (unsigned short)r;
}
__device__ __forceinline__ float bf2f(unsigned short u) {
    return __uint_as_float(((unsigned int)u) << 16);
}

__device__ __forceinline__ void gload_lds16(const void* g, void* l) {
    __builtin_amdgcn_global_load_lds(
        (const __attribute__((address_space(1))) unsigned int*)g,
        (__attribute__((address_space(3))) unsigned int*)l, 16, 0, 0);
}

// ---------------------------------------------------------------------------
// Convert x (fp32) -> xb (bf16), applying cyclic shift roll(x,-DISP) so that
// xb rows are in SHIFTED token order (GEMM A reads become linear).
// ---------------------------------------------------------------------------
__global__ __launch_bounds__(256) void cvt_x_shift(const float* __restrict__ x,
                                                   unsigned short* __restrict__ xb) {
    int idx = blockIdx.x * 256 + threadIdx.x;     // 8192*256 threads, 8 elems each
    int e0 = idx * 8;
    int r = e0 >> 9, d = e0 & 511;
    int b = r >> 12, n = r & 4095;
    const float* src = x + (size_t)((b << 12) | ((n + DISP) & 4095)) * 512 + d;
    float4 f0 = *(const float4*)src;
    float4 f1 = *(const float4*)(src + 4);
    u16x8 p;
    p[0] = f2bf(f0.x); p[1] = f2bf(f0.y); p[2] = f2bf(f0.z); p[3] = f2bf(f0.w);
    p[4] = f2bf(f1.x); p[5] = f2bf(f1.y); p[6] = f2bf(f1.z); p[7] = f2bf(f1.w);
    *(u16x8*)(xb + (size_t)r * 512 + d) = p;
}

// ---------------------------------------------------------------------------
// Convert + transpose weights: WqkvT[n][k] (1536x512), WoutT[n][k] (512x512)
// ---------------------------------------------------------------------------
__global__ __launch_bounds__(256) void cvt_w(const float* __restrict__ Wqkv,
                                             const float* __restrict__ Wout,
                                             unsigned short* __restrict__ wqkvT,
                                             unsigned short* __restrict__ woutT) {
    int idx = blockIdx.x * 256 + threadIdx.x;    // 4096*256 = 1,048,576
    if (idx < 786432) {
        int n = idx >> 9, k = idx & 511;
        wqkvT[idx] = f2bf(Wqkv[(size_t)k * 1536 + n]);
    } else {
        int j = idx - 786432;
        int n = j >> 9, k = j & 511;
        woutT[j] = f2bf(Wout[(size_t)k * 512 + n]);
    }
}

// ---------------------------------------------------------------------------
// bf16 MFMA GEMM for QKV: WINDOW-ALIGNED tiling (r10: WRITE 430->100MB) +
// double-buffered prefetch-before-compute (T3 minimal 2-phase): STAGE(t+1)
// issued BEFORE compute(t); single __syncthreads per K-step whose vmcnt
// drain lands AFTER compute -> HBM latency hides under MFMA.  BK=32.
//   window base = ((b*8+h)*32+pi)*8192   (16KB block per (b,h,window))
//   q: plain      [w][dh]            -> base + w*64 + dh
//   k: swizzled   [w][dh]            -> base + w*64 + (dh ^ ((w&7)<<3))
//   v: transposed [dh][w], swizzled  -> base + dh*128 + (w ^ ((dh&7)<<3))
// ---------------------------------------------------------------------------
__global__ __launch_bounds__(256) void gemm_qkv(const unsigned short* __restrict__ A,
                                                const unsigned short* __restrict__ BT,
                                                unsigned short* __restrict__ qw,
                                                unsigned short* __restrict__ kw,
                                                unsigned short* __restrict__ vw) {
    __shared__ unsigned short As[2][128 * 32];   // 2 x 8KB
    __shared__ unsigned short Bs[2][128 * 32];   // 2 x 8KB
    const int tid  = threadIdx.x;
    const int wv   = tid >> 6, lane = tid & 63;
    const int brow = blockIdx.x;            // 256 = b*32 + pi
    const int bcol = blockIdx.y;            // 12
    const int b  = brow >> 5, pi = brow & 31;
    const int wr = (wv >> 1) * 64, wc = (wv & 1) * 64;
    const int lr = lane >> 4, lc = lane & 15;
    const int kq = lr * 8;

    f32x4_t acc[4][4];
#pragma unroll
    for (int i = 0; i < 4; ++i)
#pragma unroll
        for (int j = 0; j < 4; ++j) acc[i][j] = (f32x4_t)0.f;

    // A row for tile-row m (= window token w): b*4096 + m*32 + pi
    const size_t abase = ((size_t)b * 4096 + pi) * 512;
    const size_t brow0 = (size_t)bcol * 128;

    // stage one 128x32 tile pair into buffer BUF at K-offset K0S.
    // 8 chunks of 512 elems; wave wv owns chunks 2wv, 2wv+1.
#define STAGE_Q(BUF, K0S) do {                                                   \
    _Pragma("unroll")                                                            \
    for (int i_ = 0; i_ < 2; ++i_) {                                             \
        int chunk_ = wv * 2 + i_;                                                \
        int idx_ = chunk_ * 64 + lane;                                           \
        int row_ = idx_ >> 2;                                                    \
        int koff_ = (idx_ & 3) * 8;                                              \
        gload_lds16(A  + abase + (size_t)row_ * 16384 + (K0S) + koff_,           \
                    &As[BUF][chunk_ * 512]);                                     \
        gload_lds16(BT + (brow0 + row_) * 512 + (K0S) + koff_,                   \
                    &Bs[BUF][chunk_ * 512]);                                     \
    } } while (0)

#define COMPUTE_Q(BUF) do {                                                      \
    bf16x8_t af_[4], bf_[4];                                                     \
    _Pragma("unroll")                                                            \
    for (int mi_ = 0; mi_ < 4; ++mi_)                                            \
        af_[mi_] = *(const bf16x8_t*)&As[BUF][(wr + mi_ * 16 + lc) * 32 + kq];   \
    _Pragma("unroll")                                                            \
    for (int nj_ = 0; nj_ < 4; ++nj_)                                            \
        bf_[nj_] = *(const bf16x8_t*)&Bs[BUF][(wc + nj_ * 16 + lc) * 32 + kq];   \
    _Pragma("unroll")                                                            \
    for (int mi_ = 0; mi_ < 4; ++mi_)                                            \
        _Pragma("unroll")                                                        \
        for (int nj_ = 0; nj_ < 4; ++nj_)                                        \
            acc[mi_][nj_] = __builtin_amdgcn_mfma_f32_16x16x32_bf16(             \
                af_[mi_], bf_[nj_], acc[mi_][nj_], 0, 0, 0);                     \
    } while (0)

    // prologue: tile 0 -> buf 0
    STAGE_Q(0, 0);
    __syncthreads();
    // main: 16 K-tiles, static double-buffer (tiles 2t,2t+1 per pair)
#pragma unroll 1
    for (int t = 0; t < 7; ++t) {
        STAGE_Q(1, (2 * t + 1) * 32);
        COMPUTE_Q(0);
        __syncthreads();
        STAGE_Q(0, (2 * t + 2) * 32);
        COMPUTE_Q(1);
        __syncthreads();
    }
    STAGE_Q(1, 15 * 32);
    COMPUTE_Q(0);
    __syncthreads();
    COMPUTE_Q(1);
#undef STAGE_Q
#undef COMPUTE_Q

    // Epilogue: C row = (lane>>4)*4+reg (= token w), col = lane&15 in frag
#pragma unroll
    for (int nj = 0; nj < 4; ++nj) {
        int c = bcol * 128 + wc + nj * 16 + lc;
        int which = c >> 9;
        int h  = (c >> 6) & 7;
        int dh = c & 63;
        unsigned short* dst = (which == 0) ? qw : ((which == 1) ? kw : vw);
        size_t base = ((size_t)((b * 8 + h) * 32 + pi)) * 8192;
#pragma unroll
        for (int mi = 0; mi < 4; ++mi)
#pragma unroll
            for (int r = 0; r < 4; ++r) {
                int w = wr + mi * 16 + lr * 4 + r;   // tile row = window token
                size_t off;
                if (which == 0)      off = base + (size_t)w * 64 + dh;
                else if (which == 1) off = base + (size_t)w * 64 + (dh ^ ((w & 7) << 3));
                else                 off = base + (size_t)dh * 128 + (w ^ ((dh & 7) << 3));
                dst[off] = f2bf(acc[mi][nj][r]);
            }
    }
}

// ---------------------------------------------------------------------------
// out_proj GEMM: out = roll(ao @ Wout + bout, +DISP).  Same dbuf structure.
// ---------------------------------------------------------------------------
__global__ __launch_bounds__(256) void gemm_out(const unsigned short* __restrict__ A,
                                                const unsigned short* __restrict__ BT,
                                                const float* __restrict__ bout,
                                                float* __restrict__ out) {
    __shared__ unsigned short As[2][128 * 32];
    __shared__ unsigned short Bs[2][128 * 32];
    const int tid  = threadIdx.x;
    const int wv   = tid >> 6, lane = tid & 63;
    const int brow = blockIdx.x;            // 256
    const int bcol = blockIdx.y;            // 4
    const int wr = (wv >> 1) * 64, wc = (wv & 1) * 64;
    const int lr = lane >> 4, lc = lane & 15;
    const int kq = lr * 8;

    f32x4_t acc[4][4];
#pragma unroll
    for (int i = 0; i < 4; ++i)
#pragma unroll
        for (int j = 0; j < 4; ++j) acc[i][j] = (f32x4_t)0.f;

    const size_t arow0 = (size_t)brow * 128;
    const size_t brow0 = (size_t)bcol * 128;

#define STAGE_O(BUF, K0S) do {                                                   \
    _Pragma("unroll")                                                            \
    for (int i_ = 0; i_ < 2; ++i_) {                                             \
        int chunk_ = wv * 2 + i_;                                                \
        int idx_ = chunk_ * 64 + lane;                                           \
        int row_ = idx_ >> 2;                                                    \
        int koff_ = (idx_ & 3) * 8;                                              \
        gload_lds16(A  + (arow0 + row_) * 512 + (K0S) + koff_,                   \
                    &As[BUF][chunk_ * 512]);                                     \
        gload_lds16(BT + (brow0 + row_) * 512 + (K0S) + koff_,                   \
                    &Bs[BUF][chunk_ * 512]);                                     \
    } } while (0)

#define COMPUTE_O(BUF) do {                                                      \
    bf16x8_t af_[4], bf_[4];                                                     \
    _Pragma("unroll")                                                            \
    for (int mi_ = 0; mi_ < 4; ++mi_)                                            \
        af_[mi_] = *(const bf16x8_t*)&As[BUF][(wr + mi_ * 16 + lc) * 32 + kq];   \
    _Pragma("unroll")                                                            \
    for (int nj_ = 0; nj_ < 4; ++nj_)                                            \
        bf_[nj_] = *(const bf16x8_t*)&Bs[BUF][(wc + nj_ * 16 + lc) * 32 + kq];   \
    _Pragma("unroll")                                                            \
    for (int mi_ = 0; mi_ < 4; ++mi_)                                            \
        _Pragma("unroll")                                                        \
        for (int nj_ = 0; nj_ < 4; ++nj_)                                        \
            acc[mi_][nj_] = __builtin_amdgcn_mfma_f32_16x16x32_bf16(             \
                af_[mi_], bf_[nj_], acc[mi_][nj_], 0, 0, 0);                     \
    } while (0)

    STAGE_O(0, 0);
    __syncthreads();
#pragma unroll 1
    for (int t = 0; t < 7; ++t) {
        STAGE_O(1, (2 * t + 1) * 32);
        COMPUTE_O(0);
        __syncthreads();
        STAGE_O(0, (2 * t + 2) * 32);
        COMPUTE_O(1);
        __syncthreads();
    }
    STAGE_O(1, 15 * 32);
    COMPUTE_O(0);
    __syncthreads();
    COMPUTE_O(1);
#undef STAGE_O
#undef COMPUTE_O

#pragma unroll
    for (int nj = 0; nj < 4; ++nj) {
        int c = bcol * 128 + wc + nj * 16 + lc;
        float bias = bout[c];
#pragma unroll
        for (int mi = 0; mi < 4; ++mi)
#pragma unroll
            for (int r = 0; r < 4; ++r) {
                int row = brow * 128 + wr + mi * 16 + lr * 4 + r;
                int b = row >> 12, np = row & 4095;
                int dn = (np + DISP) & 4095;                 // roll(+DISP)
                out[(size_t)((b << 12) | dn) * 512 + c] = acc[mi][nj][r] + bias;
            }
    }
}

// ---------------------------------------------------------------------------
// win_attn (MFMA): one block per (b,h,pi) window; 4 waves, wave wv owns
// q-rows [wv*32, wv*32+32).  S kept in accumulators; wave-parallel softmax;
// P through per-wave swizzled LDS; PV via MFMA with transposed V.
// ---------------------------------------------------------------------------
__global__ __launch_bounds__(256) void win_attn(const unsigned short* __restrict__ qw,
                                                const unsigned short* __restrict__ kw,
                                                const unsigned short* __restrict__ vw,
                                                const float* __restrict__ pos,
                                                unsigned short* __restrict__ aob) {
    __shared__ unsigned short K_lds[8192];        // 16KB, [w][dh] swizzled
    __shared__ unsigned short V_lds[8192];        // 16KB, [dh][w] swizzled
    __shared__ unsigned short P_lds[4][4096];     // 8KB per wave, [r][j] swizzled
    __shared__ float pos_lds[255];

    const int tid  = threadIdx.x;
    const int wv   = tid >> 6, lane = tid & 63;
    const int lr   = lane >> 4, lc = lane & 15;
    const int blk  = blockIdx.x;        // b*256 + h*32 + pi
    const int pi   = blk & 31;
    const int h    = (blk >> 5) & 7;
    const int b    = blk >> 8;
    const size_t base = ((size_t)((b * 8 + h) * 32 + pi)) * 8192;
    const unsigned short* qg = qw + base;
    const unsigned short* kg = kw + base;
    const unsigned short* vg = vw + base;

    if (tid < 255) pos_lds[tid] = pos[tid];

    // stage K, V linearly (global layout == LDS image)
#pragma unroll
    for (int i = 0; i < 4; ++i) {
        int c = wv * 4 + i;
        gload_lds16(kg + c * 512 + lane * 8, &K_lds[c * 512]);
        gload_lds16(vg + c * 512 + lane * 8, &V_lds[c * 512]);
    }

    // Q fragments direct from global (plain [w][dh] layout)
    bf16x8_t qf[2][2];
#pragma unroll
    for (int mi = 0; mi < 2; ++mi)
#pragma unroll
        for (int ks = 0; ks < 2; ++ks)
            qf[mi][ks] = *(const bf16x8_t*)(qg + (wv * 32 + mi * 16 + lc) * 64 + ks * 32 + lr * 8);

    __syncthreads();

    // ---- QK^T: S[32][128] per wave in accumulators -------------------------
    f32x4_t sa[2][8];
#pragma unroll
    for (int mi = 0; mi < 2; ++mi)
#pragma unroll
        for (int nj = 0; nj < 8; ++nj) sa[mi][nj] = (f32x4_t)0.f;

#pragma unroll
    for (int ks = 0; ks < 2; ++ks) {
#pragma unroll
        for (int nj = 0; nj < 8; ++nj) {
            int row = nj * 16 + lc;
            int byteoff = ((row * 128) + (ks * 32 + lr * 8) * 2) ^ ((row & 7) << 4);
            bf16x8_t kf = *(const bf16x8_t*)((const char*)K_lds + byteoff);
            sa[0][nj] = __builtin_amdgcn_mfma_f32_16x16x32_bf16(qf[0][ks], kf, sa[0][nj], 0, 0, 0);
            sa[1][nj] = __builtin_amdgcn_mfma_f32_16x16x32_bf16(qf[1][ks], kf, sa[1][nj], 0, 0, 0);
        }
    }

    // ---- bias + mask + wave-parallel softmax; P -> per-wave LDS (bf16) -----
    // lane holds S[i][j]: i = wv*32 + mi*16 + lr*4 + r, j = nj*16 + lc
#pragma unroll
    for (int mi = 0; mi < 2; ++mi)
#pragma unroll
        for (int r = 0; r < 4; ++r) {
            int i = wv * 32 + mi * 16 + lr * 4 + r;
            float mx = -3.0e38f;
#pragma unroll
            for (int nj = 0; nj < 8; ++nj) {
                int j = nj * 16 + lc;
                float s = fmaf(sa[mi][nj][r], 0.125f, pos_lds[j - i + 127]);
                if ((i >= 64) != (j >= 64)) s -= 1e9f;   // shift mask
                sa[mi][nj][r] = s;
                mx = fmaxf(mx, s);
            }
            mx = fmaxf(mx, __shfl_xor(mx, 1));
            mx = fmaxf(mx, __shfl_xor(mx, 2));
            mx = fmaxf(mx, __shfl_xor(mx, 4));
            mx = fmaxf(mx, __shfl_xor(mx, 8));
            float sum = 0.f;
#pragma unroll
            for (int nj = 0; nj < 8; ++nj) {
                float e = __expf(sa[mi][nj][r] - mx);
                sa[mi][nj][r] = e;
                sum += e;
            }
            sum += __shfl_xor(sum, 1);
            sum += __shfl_xor(sum, 2);
            sum += __shfl_xor(sum, 4);
            sum += __shfl_xor(sum, 8);
            float inv = 1.0f / sum;
            int rloc = mi * 16 + lr * 4 + r;
#pragma unroll
            for (int nj = 0; nj < 8; ++nj) {
                int j = nj * 16 + lc;
                int byteoff = ((rloc * 256) + j * 2) ^ ((rloc & 7) << 4);
                *(unsigned short*)((char*)P_lds[wv] + byteoff) = f2bf(sa[mi][nj][r] * inv);
            }
        }
    // (no barrier: P_lds[wv] is same-wave RAW; compiler inserts lgkmcnt)

    // ---- PV: O[32][64] per wave ------------------------------------------
    f32x4_t oa[2][4];
#pragma unroll
    for (int mi = 0; mi < 2; ++mi)
#pragma unroll
        for (int nj = 0; nj < 4; ++nj) oa[mi][nj] = (f32x4_t)0.f;

#pragma unroll
    for (int ks = 0; ks < 4; ++ks) {
        bf16x8_t pa[2], vb[4];
#pragma unroll
        for (int mi = 0; mi < 2; ++mi) {
            int rloc = mi * 16 + lc;
            int byteoff = ((rloc * 256) + (ks * 32 + lr * 8) * 2) ^ ((rloc & 7) << 4);
            pa[mi] = *(const bf16x8_t*)((const char*)P_lds[wv] + byteoff);
        }
#pragma unroll
        for (int nj = 0; nj < 4; ++nj) {
            int dh = nj * 16 + lc;
            int byteoff = ((dh * 256) + (ks * 32 + lr * 8) * 2) ^ ((dh & 7) << 4);
            vb[nj] = *(const bf16x8_t*)((const char*)V_lds + byteoff);
        }
#pragma unroll
        for (int mi = 0; mi < 2; ++mi)
#pragma unroll
            for (int nj = 0; nj < 4; ++nj)
                oa[mi][nj] = __builtin_amdgcn_mfma_f32_16x16x32_bf16(pa[mi], vb[nj], oa[mi][nj], 0, 0, 0);
    }

    // ---- epilogue: O row w -> ao token n' = pi*128 + w ---------------------
    const size_t orow0 = (size_t)b * 4096 + (size_t)pi * 128;
#pragma unroll
    for (int mi = 0; mi < 2; ++mi)
#pragma unroll
        for (int r = 0; r < 4; ++r) {
            int w = wv * 32 + mi * 16 + lr * 4 + r;
            unsigned short* dst = aob + (orow0 + w) * 512 + h * 64;
#pragma unroll
            for (int nj = 0; nj < 4; ++nj)
                dst[nj * 16 + lc] = f2bf(oa[mi][nj][r]);
        }
}

// ---------------------------------------------------------------------------
extern "C" void kernel_launch(void* const* d_in, const int* in_sizes, int n_in,
                              void* d_out, int out_size, void* d_ws, size_t ws_size,
                              hipStream_t stream) {
    (void)in_sizes; (void)n_in; (void)out_size; (void)ws_size;
    const float* x    = (const float*)d_in[0];
    const float* Wqkv = (const float*)d_in[1];
    const float* pos  = (const float*)d_in[2];
    const float* Wout = (const float*)d_in[3];
    const float* bout = (const float*)d_in[4];
    float* out = (float*)d_out;

    const size_t T = (size_t)BB * NN * 512;   // 16,777,216 elems
    unsigned short* xb    = (unsigned short*)d_ws;
    unsigned short* wqkvT = xb + T;           // 786,432
    unsigned short* woutT = wqkvT + 786432;   // 262,144
    unsigned short* qw    = woutT + 262144;
    unsigned short* kw    = qw + T;
    unsigned short* vw    = kw + T;
    unsigned short* aob   = vw + T;

    cvt_x_shift<<<dim3(8192), 256, 0, stream>>>(x, xb);
    cvt_w<<<dim3(4096), 256, 0, stream>>>(Wqkv, Wout, wqkvT, woutT);
    gemm_qkv<<<dim3(256, 12), 256, 0, stream>>>(xb, wqkvT, qw, kw, vw);
    win_attn<<<dim3(2048), 256, 0, stream>>>(qw, kw, vw, pos, aob);
    gemm_out<<<dim3(256, 4), 256, 0, stream>>>(aob, woutT, bout, out);
}